// Round 4
// baseline (601.975 us; speedup 1.0000x reference)
//
#include <hip/hip_runtime.h>
#include <hip/hip_cooperative_groups.h>
#include <hip/hip_bf16.h>
#include <math.h>

namespace cg = cooperative_groups;

#define N_NODES 50000
#define N_EDGES 800000
#define IN_C 128
#define HID_C 96
#define OUT_C 64
#define BN_EPS 1e-5f

// ELL edge storage: 64 slots/row. deg ~ Poisson(16); P(deg>64) ~ 1e-17 —
// slot>=64 is guarded (skip) to protect memory, never expected to fire.
#define ELL_SHIFT 6
#define ELL_CAP   64

// XCD routing for the ELL fill (R13 winner).
#define NGRP 8
#define GRP_ROWS ((N_NODES + NGRP - 1) / NGRP)   // 6250

// Packed ELL entry: col in low 16 bits (N_NODES < 65536), edge weight as
// 16-bit fixed point in high bits (ew in [0,1); abs err 7.6e-6).
#define EW_SCALE 65535.0f
#define EW_INV   (1.0f / 65535.0f)

// BN stats atomic slicing: 4 slices cut per-address atomic chains 4x.
#define ST_SLICES 4

// LDS overlay for the mega kernel: union of phase needs.
// gemm L1 (K=128,J=96): (64+96)*136*2 = 43520 B (+scsh unused)
// gemm L2 (K=96,J=96):  (64+96)*104*2 = 33280 + 768 = 34048 B
// agg:                  2*16*24*4 = 3072 B
#define SMEM_BYTES 43584

typedef __attribute__((ext_vector_type(8))) short short8;   // 8 bf16 = 4 VGPRs
typedef __attribute__((ext_vector_type(4))) float f32x4;    // MFMA acc

static __device__ __forceinline__ unsigned short f2b(float f) {
    __hip_bfloat16 b = __float2bfloat16(f);   // RNE
    return *reinterpret_cast<unsigned short*>(&b);
}
static __device__ __forceinline__ float b2f(unsigned short u) {
    return __uint_as_float((unsigned)u << 16);  // exact
}
static __device__ __forceinline__ unsigned pack2(float a, float b) {
    return (unsigned)f2b(a) | ((unsigned)f2b(b) << 16);
}

// Unpack 8 bf16 from a uint4 and FMA into acc[B..B+7].
#define FMA8(B, V, W)                                          \
    acc[(B) + 0] += (W) * __uint_as_float((V).x << 16);        \
    acc[(B) + 1] += (W) * __uint_as_float((V).x & 0xffff0000u);\
    acc[(B) + 2] += (W) * __uint_as_float((V).y << 16);        \
    acc[(B) + 3] += (W) * __uint_as_float((V).y & 0xffff0000u);\
    acc[(B) + 4] += (W) * __uint_as_float((V).z << 16);        \
    acc[(B) + 5] += (W) * __uint_as_float((V).z & 0xffff0000u);\
    acc[(B) + 6] += (W) * __uint_as_float((V).w << 16);        \
    acc[(B) + 7] += (W) * __uint_as_float((V).w & 0xffff0000u);

// ===========================================================================
// Shared phase bodies (used by the mega kernel; standalone kernels below
// reuse the same logic for the non-cooperative fallback path).
// ===========================================================================

// ---- prep: weight transpose + cnt zero + stats zero (grid-strided) --------
static __device__ __forceinline__ void prep_body(
    int i, const float* W1, const float* W2, const float* W3,
    unsigned short* Wt1, unsigned short* Wt2, unsigned short* Wt3,
    int* cnt, float* stats) {
    const int n1 = IN_C * HID_C, n2 = HID_C * HID_C, n3 = HID_C * OUT_C;
    if (i < n1) {
        int j = i / IN_C, k = i % IN_C;
        Wt1[i] = f2b(W1[k * HID_C + j]);
    } else if (i < n1 + n2) {
        int t = i - n1, j = t / HID_C, k = t % HID_C;
        Wt2[t] = f2b(W2[k * HID_C + j]);
    } else if (i < n1 + n2 + n3) {
        int t = i - n1 - n2, j = t / HID_C, k = t % HID_C;
        Wt3[t] = f2b(W3[k * OUT_C + j]);
    }
    if (i < N_NODES) cnt[i] = 0;
    if (i < 2 * ST_SLICES * 2 * HID_C) stats[i] = 0.f;   // stats1|stats2
}

// ---- fill: XCD-routed ELL scatter (R13) -----------------------------------
static __device__ __forceinline__ void fill_body(
    int grp, int e, const int* row, const int* col, const float* ew,
    int* cnt, unsigned int* pairs) {
    if (e >= N_EDGES) return;
    int r = row[e];
    int lo = grp * GRP_ROWS;
    if ((unsigned)(r - lo) >= (unsigned)GRP_ROWS) return;   // not my group
    int slot = atomicAdd(&cnt[r], 1);
    if (slot < ELL_CAP) {
        unsigned wq = (unsigned)(ew[e] * EW_SCALE + 0.5f);  // [0,1) -> u16
        pairs[((size_t)r << ELL_SHIFT) + slot] = (wq << 16) | (unsigned)col[e];
    }
}

// ---- MFMA GEMM phase (tile-strided; LDS via smem overlay) -----------------
// mfma_f32_16x16x32_bf16 layouts (HW-verified):
//   A: lane holds X[m=lane&15][k=(lane>>4)*8+j]
//   B: lane holds W[k=(lane>>4)*8+j][n=lane&15]  (= row n of W^T)
//   D: lane,reg r -> row m=(lane>>4)*4+r, col n=lane&15
template <int K, int J, bool APPLY, bool XBF16>
static __device__ __forceinline__ void gemm_phase(
    unsigned char* smem, const void* xin, const unsigned short* Wt,
    const float* stats, const float* gamma, const float* beta,
    unsigned short* h, int gridSz) {
    constexpr int MT = 64;
    constexpr int SK = K + 8;
    constexpr int NT = J / 16;
    unsigned short* Xs = (unsigned short*)smem;          // MT*SK shorts
    unsigned short* Ws = Xs + MT * SK;                   // J*SK shorts
    float* scsh = (float*)(smem + (size_t)(MT + J) * SK * 2);  // 2*K floats

    int tid = threadIdx.x;

    if (APPLY) {
        if (tid < K) {
            float s = 0.f, sq = 0.f;
#pragma unroll
            for (int sl = 0; sl < ST_SLICES; ++sl) {
                s  += stats[sl * 2 * K + tid];
                sq += stats[sl * 2 * K + K + tid];
            }
            const float invN = 1.f / N_NODES;
            float mean = s * invN;
            float var = sq * invN - mean * mean;
            float sc = gamma[tid] * rsqrtf(var + BN_EPS);
            scsh[tid] = sc;
            scsh[K + tid] = beta[tid] - mean * sc;
        }
    }
    // Ws staged once per block (tables are tile-invariant).
    for (int i = tid; i < J * (K / 4); i += 256) {
        int j = i / (K / 4), kq = i % (K / 4);
        *(ushort4*)&Ws[j * SK + kq * 4] =
            *(const ushort4*)(Wt + (size_t)j * K + kq * 4);
    }
    __syncthreads();   // scsh + Ws ready (Xs staging below reads scsh)

    int lane = tid & 63;
    int w = tid >> 6;
    int m16 = lane & 15;
    int quad = lane >> 4;
    const int nTiles = (N_NODES + MT - 1) / MT;

    for (int tile = blockIdx.x; tile < nTiles; tile += gridSz) {
        int tileBase = tile * MT;

        if (XBF16) {
            const unsigned short* xb = (const unsigned short*)xin;
            for (int i = tid; i < MT * (K / 8); i += 256) {
                int node = i / (K / 8), kq = i % (K / 8);
                int gn = min(tileBase + node, N_NODES - 1);
                const unsigned short* src = xb + (size_t)gn * K + kq * 8;
                ushort4 u0 = *(const ushort4*)(src);
                ushort4 u1 = *(const ushort4*)(src + 4);
                if (APPLY) {
                    int kb = kq * 8;
                    float v0 = fmaxf(b2f(u0.x) * scsh[kb + 0] + scsh[K + kb + 0], 0.f);
                    float v1 = fmaxf(b2f(u0.y) * scsh[kb + 1] + scsh[K + kb + 1], 0.f);
                    float v2 = fmaxf(b2f(u0.z) * scsh[kb + 2] + scsh[K + kb + 2], 0.f);
                    float v3 = fmaxf(b2f(u0.w) * scsh[kb + 3] + scsh[K + kb + 3], 0.f);
                    float v4 = fmaxf(b2f(u1.x) * scsh[kb + 4] + scsh[K + kb + 4], 0.f);
                    float v5 = fmaxf(b2f(u1.y) * scsh[kb + 5] + scsh[K + kb + 5], 0.f);
                    float v6 = fmaxf(b2f(u1.z) * scsh[kb + 6] + scsh[K + kb + 6], 0.f);
                    float v7 = fmaxf(b2f(u1.w) * scsh[kb + 7] + scsh[K + kb + 7], 0.f);
                    u0 = make_ushort4(f2b(v0), f2b(v1), f2b(v2), f2b(v3));
                    u1 = make_ushort4(f2b(v4), f2b(v5), f2b(v6), f2b(v7));
                }
                *(ushort4*)&Xs[node * SK + kq * 8] = u0;
                *(ushort4*)&Xs[node * SK + kq * 8 + 4] = u1;
            }
        } else {
            const float* xf = (const float*)xin;
            for (int i = tid; i < MT * (K / 4); i += 256) {
                int node = i / (K / 4), kq = i % (K / 4);
                int gn = min(tileBase + node, N_NODES - 1);
                float4 v = *(const float4*)(xf + (size_t)gn * K + kq * 4);
                ushort4 o = make_ushort4(f2b(v.x), f2b(v.y), f2b(v.z), f2b(v.w));
                *(ushort4*)&Xs[node * SK + kq * 4] = o;
            }
        }
        __syncthreads();

        f32x4 acc[NT];
#pragma unroll
        for (int nt = 0; nt < NT; ++nt) acc[nt] = (f32x4){0.f, 0.f, 0.f, 0.f};

        const unsigned short* xrow = &Xs[(w * 16 + m16) * SK];
#pragma unroll
        for (int k0 = 0; k0 < K; k0 += 32) {
            short8 a = *(const short8*)(xrow + k0 + quad * 8);
#pragma unroll
            for (int nt = 0; nt < NT; ++nt) {
                short8 b = *(const short8*)&Ws[(nt * 16 + m16) * SK + k0 + quad * 8];
                acc[nt] = __builtin_amdgcn_mfma_f32_16x16x32_bf16(a, b, acc[nt], 0, 0, 0);
            }
        }

#pragma unroll
        for (int nt = 0; nt < NT; ++nt) {
#pragma unroll
            for (int r = 0; r < 4; ++r) {
                int node = tileBase + w * 16 + quad * 4 + r;
                if (node < N_NODES)
                    h[(size_t)node * J + nt * 16 + m16] = f2b(acc[nt][r]);
            }
        }
        __syncthreads();   // WAR: protect Xs before next tile's restage
    }
}

// ---- fused ELL aggregation phase (tile-strided) ---------------------------
template <int D, bool LSM, bool STATS>
static __device__ __forceinline__ void agg_phase(
    unsigned char* smem, const unsigned short* h, const int* cnt,
    const unsigned int* pairs, unsigned short* outb, float* outf,
    const float* b3, float* stats, int gridSz) {
    constexpr int TPN = 4;
    constexpr int C = D / TPN;        // 24 (D=96) or 16 (D=64)
    constexpr int NPB = 256 / TPN;    // 64 nodes per block
    float* shS = (float*)smem;        // 16*C
    float* shQ = shS + 16 * C;        // 16*C

    int tid = threadIdx.x;
    int q = tid & 3;
    int nloc = tid >> 2;
    const int nTiles = (N_NODES + NPB - 1) / NPB;

    for (int tile = blockIdx.x; tile < nTiles; tile += gridSz) {
        int n = tile * NPB + nloc;
        bool valid = n < N_NODES;
        int nn = valid ? n : N_NODES - 1;
        int end = valid ? min(cnt[nn], ELL_CAP) : 0;
        const unsigned* ep = pairs + ((size_t)nn << ELL_SHIFT);
        const int cbase = q * C;

        float acc[C];
#pragma unroll
        for (int c = 0; c < C; ++c) acc[c] = 0.f;

        int i = 0;
        for (; i + 1 < end; i += 2) {
            unsigned p0 = ep[i], p1 = ep[i + 1];
            float w0 = (float)(p0 >> 16) * EW_INV;
            float w1 = (float)(p1 >> 16) * EW_INV;
            const unsigned short* r0 = h + (size_t)(p0 & 0xFFFFu) * D + cbase;
            const unsigned short* r1 = h + (size_t)(p1 & 0xFFFFu) * D + cbase;
            uint4 v0[C / 8], v1[C / 8];
#pragma unroll
            for (int ch = 0; ch < C / 8; ++ch) v0[ch] = *(const uint4*)(r0 + ch * 8);
#pragma unroll
            for (int ch = 0; ch < C / 8; ++ch) v1[ch] = *(const uint4*)(r1 + ch * 8);
#pragma unroll
            for (int ch = 0; ch < C / 8; ++ch) { FMA8(ch * 8, v0[ch], w0) }
#pragma unroll
            for (int ch = 0; ch < C / 8; ++ch) { FMA8(ch * 8, v1[ch], w1) }
        }
        if (i < end) {
            unsigned p0 = ep[i];
            float w0 = (float)(p0 >> 16) * EW_INV;
            const unsigned short* r0 = h + (size_t)(p0 & 0xFFFFu) * D + cbase;
#pragma unroll
            for (int ch = 0; ch < C / 8; ++ch) {
                uint4 v = *(const uint4*)(r0 + ch * 8);
                FMA8(ch * 8, v, w0)
            }
        }

        if (LSM) {
            float v[C];
#pragma unroll
            for (int c = 0; c < C; ++c) v[c] = acc[c] + b3[cbase + c];
            float m = v[0];
#pragma unroll
            for (int c = 1; c < C; ++c) m = fmaxf(m, v[c]);
            m = fmaxf(m, __shfl_xor(m, 1));
            m = fmaxf(m, __shfl_xor(m, 2));
            float s = 0.f;
#pragma unroll
            for (int c = 0; c < C; ++c) s += expf(v[c] - m);
            s += __shfl_xor(s, 1);
            s += __shfl_xor(s, 2);
            float l = m + logf(s);
            if (valid) {
#pragma unroll
                for (int ch = 0; ch < C / 4; ++ch) {
                    float4 o = make_float4(v[ch * 4 + 0] - l, v[ch * 4 + 1] - l,
                                           v[ch * 4 + 2] - l, v[ch * 4 + 3] - l);
                    *(float4*)(outf + (size_t)n * D + cbase + ch * 4) = o;
                }
            }
        } else {
            // Round to bf16 in place (stats must see rounded values).
#pragma unroll
            for (int c = 0; c < C; ++c) acc[c] = b2f(f2b(acc[c]));
#pragma unroll
            for (int ch = 0; ch < C / 8; ++ch) {
                uint4 o;
                o.x = pack2(acc[ch * 8 + 0], acc[ch * 8 + 1]);
                o.y = pack2(acc[ch * 8 + 2], acc[ch * 8 + 3]);
                o.z = pack2(acc[ch * 8 + 4], acc[ch * 8 + 5]);
                o.w = pack2(acc[ch * 8 + 6], acc[ch * 8 + 7]);
                if (valid)
                    *(uint4*)(outb + (size_t)n * D + cbase + ch * 8) = o;
            }
            if (STATS) {
                int lane = tid & 63;
                int wv = tid >> 6;
#pragma unroll
                for (int c = 0; c < C; ++c) {
                    float s = acc[c];
                    float sq = s * s;
#pragma unroll
                    for (int msk = 4; msk < 64; msk <<= 1) {
                        s  += __shfl_xor(s, msk);
                        sq += __shfl_xor(sq, msk);
                    }
                    if (lane < 4) {
                        shS[(wv * 4 + lane) * C + c] = s;
                        shQ[(wv * 4 + lane) * C + c] = sq;
                    }
                }
                __syncthreads();
                if (tid < D) {
                    int qq = tid / C, cl = tid % C;
                    float S = 0.f, Q = 0.f;
#pragma unroll
                    for (int w2 = 0; w2 < 4; ++w2) {
                        S += shS[(w2 * 4 + qq) * C + cl];
                        Q += shQ[(w2 * 4 + qq) * C + cl];
                    }
                    int slice = blockIdx.x & (ST_SLICES - 1);
                    atomicAdd(&stats[slice * 2 * D + tid], S);
                    atomicAdd(&stats[slice * 2 * D + D + tid], Q);
                }
                __syncthreads();   // WAR on shS/shQ before next tile
            }
        }
    }
}

// ===========================================================================
// R15: cooperative mega-kernel — whole pipeline, ONE dispatch, 6 grid syncs.
// Rationale: 8 serial dispatches cost ~7 boundaries (launch+drain) and
// forbid fill||gemm1 overlap. Grid clamped to co-residency (LDS union
// 43.5KB -> 3 blocks/CU -> <=768 blocks); all phases grid-strided so any
// clamped grid is correct. grid.sync() provides the device-scope fences
// required across XCDs (G16).
// ===========================================================================
struct MegaParams {
    const float *x, *ew;
    const int *row, *col;
    const float *W1, *W2, *W3, *b3, *g1, *be1, *g2, *be2;
    unsigned short *B, *A, *Wt1, *Wt2, *Wt3;
    unsigned int *pairs;
    int *cnt;
    float *stats1, *stats2, *out;
};

__global__ __launch_bounds__(256)
void mega(MegaParams p) {
    __shared__ __align__(16) unsigned char smem[SMEM_BYTES];
    cg::grid_group grid = cg::this_grid();
    const int G = (int)gridDim.x;

    // ---- phase 0: weight transpose + cnt/stats zero ----
    for (int i = blockIdx.x * 256 + threadIdx.x; i < N_NODES; i += G * 256)
        prep_body(i, p.W1, p.W2, p.W3, p.Wt1, p.Wt2, p.Wt3, p.cnt, p.stats1);
    grid.sync();

    // ---- phase 1: gemm1 then fill (independent; natural overlap) ----
    gemm_phase<IN_C, HID_C, false, false>(smem, p.x, p.Wt1,
                                          nullptr, nullptr, nullptr, p.A, G);
    {
        const int nUnits = (N_EDGES + 255) / 256;   // 3125
        int grp = blockIdx.x & (NGRP - 1);
        for (int u = blockIdx.x >> 3; u < nUnits; u += (G >> 3))
            fill_body(grp, u * 256 + threadIdx.x, p.row, p.col, p.ew,
                      p.cnt, p.pairs);
    }
    grid.sync();

    // ---- phase 2: agg1 + BN1 stats ----
    agg_phase<HID_C, false, true>(smem, p.A, p.cnt, p.pairs, p.B,
                                  nullptr, nullptr, p.stats1, G);
    grid.sync();

    // ---- phase 3: gemm2 (fuses BN1 finalize+apply+ReLU) ----
    gemm_phase<HID_C, HID_C, true, true>(smem, p.B, p.Wt2,
                                         p.stats1, p.g1, p.be1, p.A, G);
    grid.sync();

    // ---- phase 4: agg2 + BN2 stats ----
    agg_phase<HID_C, false, true>(smem, p.A, p.cnt, p.pairs, p.B,
                                  nullptr, nullptr, p.stats2, G);
    grid.sync();

    // ---- phase 5: gemm3 (fuses BN2) ----
    gemm_phase<HID_C, OUT_C, true, true>(smem, p.B, p.Wt3,
                                         p.stats2, p.g2, p.be2, p.A, G);
    grid.sync();

    // ---- phase 6: agg3 + b3 + log_softmax -> out ----
    agg_phase<OUT_C, true, false>(smem, p.A, p.cnt, p.pairs, nullptr,
                                  p.out, p.b3, nullptr, G);
}

// ===========================================================================
// Fallback standalone kernels (R14 path) — used if cooperative launch is
// rejected (capture-unsupported / too-large). Same phase bodies.
// ===========================================================================
__global__ void prep_all(const float* __restrict__ W1, const float* __restrict__ W2,
                         const float* __restrict__ W3,
                         unsigned short* __restrict__ Wt1,
                         unsigned short* __restrict__ Wt2,
                         unsigned short* __restrict__ Wt3,
                         int* __restrict__ cnt, float* __restrict__ stats) {
    int i = blockIdx.x * blockDim.x + threadIdx.x;
    if (i < N_NODES)
        prep_body(i, W1, W2, W3, Wt1, Wt2, Wt3, cnt, stats);
}

__global__ __launch_bounds__(256)
void fill_ell(const int* __restrict__ row, const int* __restrict__ col,
              const float* __restrict__ ew, int* __restrict__ cnt,
              unsigned int* __restrict__ pairs) {
    int grp = blockIdx.x & (NGRP - 1);
    int e = (blockIdx.x >> 3) * 256 + threadIdx.x;
    fill_body(grp, e, row, col, ew, cnt, pairs);
}

template <int K, int J, bool APPLY, bool XBF16>
__global__ __launch_bounds__(256)
void gemm_mfma(const void* __restrict__ xin,
               const unsigned short* __restrict__ Wt,
               const float* __restrict__ stats,
               const float* __restrict__ gamma,
               const float* __restrict__ beta,
               unsigned short* __restrict__ h) {
    __shared__ __align__(16) unsigned char smem[SMEM_BYTES];
    gemm_phase<K, J, APPLY, XBF16>(smem, xin, Wt, stats, gamma, beta, h,
                                   (int)gridDim.x);
}

template <int D, bool LSM, bool STATS>
__global__ __launch_bounds__(256)
void agg_fused(const unsigned short* __restrict__ h,
               const int* __restrict__ cnt,
               const unsigned int* __restrict__ pairs,
               unsigned short* __restrict__ outb,
               float* __restrict__ outf,
               const float* __restrict__ b3,
               float* __restrict__ stats) {
    __shared__ __align__(16) unsigned char smem[4096];
    agg_phase<D, LSM, STATS>(smem, h, cnt, pairs, outb, outf, b3, stats,
                             (int)gridDim.x);
}

extern "C" void kernel_launch(void* const* d_in, const int* in_sizes, int n_in,
                              void* d_out, int out_size, void* d_ws, size_t ws_size,
                              hipStream_t stream) {
    const float* x   = (const float*)d_in[0];
    const float* ew  = (const float*)d_in[1];
    const int*   row = (const int*)d_in[2];
    const int*   col = (const int*)d_in[3];
    const float* W1  = (const float*)d_in[4];
    // b1 = d_in[5], b2 = d_in[7]: cancel inside BatchNorm (see gemm_phase).
    const float* W2  = (const float*)d_in[6];
    const float* W3  = (const float*)d_in[8];
    const float* b3  = (const float*)d_in[9];
    const float* g1  = (const float*)d_in[10];
    const float* be1 = (const float*)d_in[11];
    const float* g2  = (const float*)d_in[12];
    const float* be2 = (const float*)d_in[13];
    float* out = (float*)d_out;

    // Workspace layout:
    // B bf16[N*96] | A bf16[N*96] | Wt1|Wt2|Wt3 bf16 | pairs uint[N*64] |
    // cnt[N] | stats1[4*192] | stats2[4*192]
    unsigned short* B      = (unsigned short*)d_ws;
    unsigned short* A      = B + (size_t)N_NODES * HID_C;
    unsigned short* Wt1    = A + (size_t)N_NODES * HID_C;
    unsigned short* Wt2    = Wt1 + IN_C * HID_C;
    unsigned short* Wt3    = Wt2 + HID_C * HID_C;
    unsigned int*   pairs  = (unsigned int*)(Wt3 + HID_C * OUT_C);
    int*            cnt    = (int*)(pairs + ((size_t)N_NODES << ELL_SHIFT));
    float*          stats1 = (float*)(cnt + N_NODES);
    float*          stats2 = stats1 + ST_SLICES * 2 * HID_C;

    MegaParams P;
    P.x = x; P.ew = ew; P.row = row; P.col = col;
    P.W1 = W1; P.W2 = W2; P.W3 = W3; P.b3 = b3;
    P.g1 = g1; P.be1 = be1; P.g2 = g2; P.be2 = be2;
    P.B = B; P.A = A; P.Wt1 = Wt1; P.Wt2 = Wt2; P.Wt3 = Wt3;
    P.pairs = pairs; P.cnt = cnt; P.stats1 = stats1; P.stats2 = stats2;
    P.out = out;

    // Co-residency clamp: occupancy API accounts VGPR+LDS. LDS 43.5KB ->
    // expect 3 blocks/CU -> 768 blocks. Multiple of 16 (fill needs %8==0).
    bool done = false;
    int nb = 0;
    if (hipOccupancyMaxActiveBlocksPerMultiprocessor(&nb, mega, 256, 0)
            == hipSuccess && nb > 0) {
        int G = nb * 256;
        if (G > 768) G = 768;
        G &= ~15;
        if (G >= 16) {
            void* args[] = { (void*)&P };
            if (hipLaunchCooperativeKernel(mega, dim3(G), dim3(256),
                                           args, 0, stream) == hipSuccess)
                done = true;
        }
    }

    if (!done) {
        // R14 fallback path (8 dispatches).
        const int T = 256;
        const int gridE = (N_EDGES + T - 1) / T;
        const int gridG = (N_NODES + 63) / 64;
        const int gridP = (N_NODES + T - 1) / T;

        prep_all<<<gridP, T, 0, stream>>>(W1, W2, W3, Wt1, Wt2, Wt3, cnt, stats1);
        fill_ell<<<gridE * NGRP, T, 0, stream>>>(row, col, ew, cnt, pairs);

        gemm_mfma<IN_C, HID_C, false, false><<<gridG, T, 0, stream>>>(
            x, Wt1, nullptr, nullptr, nullptr, A);
        agg_fused<HID_C, false, true><<<gridG, T, 0, stream>>>(
            A, cnt, pairs, B, nullptr, nullptr, stats1);

        gemm_mfma<HID_C, HID_C, true, true><<<gridG, T, 0, stream>>>(
            B, Wt2, stats1, g1, be1, A);
        agg_fused<HID_C, false, true><<<gridG, T, 0, stream>>>(
            A, cnt, pairs, B, nullptr, nullptr, stats2);

        gemm_mfma<HID_C, OUT_C, true, true><<<gridG, T, 0, stream>>>(
            B, Wt3, stats2, g2, be2, A);
        agg_fused<OUT_C, true, false><<<gridG, T, 0, stream>>>(
            A, cnt, pairs, nullptr, out, b3, nullptr);
    }
}

// Round 5
// 338.986 us; speedup vs baseline: 1.7758x; 1.7758x over previous
//
#include <hip/hip_runtime.h>
#include <hip/hip_bf16.h>
#include <math.h>

#define N_NODES 50000
#define N_EDGES 800000
#define IN_C 128
#define HID_C 96
#define OUT_C 64
#define BN_EPS 1e-5f

// ELL edge storage: 64 slots/row. deg ~ Poisson(16); P(deg>64) ~ 1e-17 —
// slot>=64 is guarded (skip) to protect memory, never expected to fire.
#define ELL_SHIFT 6
#define ELL_CAP   64

// XCD routing for the ELL fill (R13 winner).
#define NGRP 8
#define GRP_ROWS ((N_NODES + NGRP - 1) / NGRP)   // 6250

// Packed ELL entry: col in low 16 bits (N_NODES < 65536), edge weight as
// 16-bit fixed point in high bits (ew in [0,1); abs err 7.6e-6).
#define EW_SCALE 65535.0f
#define EW_INV   (1.0f / 65535.0f)

// BN stats atomic slicing: 4 slices cut per-address atomic chains 4x.
#define ST_SLICES 4

// Channel-slice width for the sliced h/B tables (R16): 96 = 4 x 24.
#define SLC 24

typedef __attribute__((ext_vector_type(8))) short short8;   // 8 bf16 = 4 VGPRs
typedef __attribute__((ext_vector_type(4))) float f32x4;    // MFMA acc

static __device__ __forceinline__ unsigned short f2b(float f) {
    __hip_bfloat16 b = __float2bfloat16(f);   // RNE
    return *reinterpret_cast<unsigned short*>(&b);
}
static __device__ __forceinline__ float b2f(unsigned short u) {
    return __uint_as_float((unsigned)u << 16);  // exact
}
static __device__ __forceinline__ unsigned pack2(float a, float b) {
    return (unsigned)f2b(a) | ((unsigned)f2b(b) << 16);
}

// Unpack 8 bf16 from a uint4 and FMA into acc[B..B+7].
#define FMA8(B, V, W)                                          \
    acc[(B) + 0] += (W) * __uint_as_float((V).x << 16);        \
    acc[(B) + 1] += (W) * __uint_as_float((V).x & 0xffff0000u);\
    acc[(B) + 2] += (W) * __uint_as_float((V).y << 16);        \
    acc[(B) + 3] += (W) * __uint_as_float((V).y & 0xffff0000u);\
    acc[(B) + 4] += (W) * __uint_as_float((V).z << 16);        \
    acc[(B) + 5] += (W) * __uint_as_float((V).z & 0xffff0000u);\
    acc[(B) + 6] += (W) * __uint_as_float((V).w << 16);        \
    acc[(B) + 7] += (W) * __uint_as_float((V).w & 0xffff0000u);

// ---------------------------------------------------------------------------
// Prep (single launch): W[K][J] fp32 -> Wt[J][K] bf16 for all layers, zero
// the ELL counters, zero BN stats (2 buffers x 4 slices x 2*96 floats).
// ---------------------------------------------------------------------------
__global__ void prep_all(const float* __restrict__ W1, const float* __restrict__ W2,
                         const float* __restrict__ W3,
                         unsigned short* __restrict__ Wt1,
                         unsigned short* __restrict__ Wt2,
                         unsigned short* __restrict__ Wt3,
                         int* __restrict__ cnt, float* __restrict__ stats) {
    int i = blockIdx.x * blockDim.x + threadIdx.x;
    const int n1 = IN_C * HID_C, n2 = HID_C * HID_C, n3 = HID_C * OUT_C;
    if (i < n1) {
        int j = i / IN_C, k = i % IN_C;
        Wt1[i] = f2b(W1[k * HID_C + j]);
    } else if (i < n1 + n2) {
        int t = i - n1, j = t / HID_C, k = t % HID_C;
        Wt2[t] = f2b(W2[k * HID_C + j]);
    } else if (i < n1 + n2 + n3) {
        int t = i - n1 - n2, j = t / HID_C, k = t % HID_C;
        Wt3[t] = f2b(W3[k * OUT_C + j]);
    }
    if (i < N_NODES) cnt[i] = 0;
    if (i < 2 * ST_SLICES * 2 * HID_C) stats[i] = 0.f;   // stats1|stats2
}

// ---------------------------------------------------------------------------
// ELL fill, XCD-routed (R13 winner; fill 53us -> under the 43us prof floor).
// ---------------------------------------------------------------------------
__global__ __launch_bounds__(256)
void fill_ell(const int* __restrict__ row, const int* __restrict__ col,
              const float* __restrict__ ew, int* __restrict__ cnt,
              unsigned int* __restrict__ pairs) {
    int g = blockIdx.x & (NGRP - 1);          // row-group -> XCD (heuristic)
    int e = (blockIdx.x >> 3) * 256 + threadIdx.x;
    if (e >= N_EDGES) return;
    int r = row[e];
    int lo = g * GRP_ROWS;
    if ((unsigned)(r - lo) >= (unsigned)GRP_ROWS) return;   // not my group
    int slot = atomicAdd(&cnt[r], 1);
    if (slot < ELL_CAP) {
        unsigned wq = (unsigned)(ew[e] * EW_SCALE + 0.5f);  // [0,1) -> u16
        pairs[((size_t)r << ELL_SHIFT) + slot] = (wq << 16) | (unsigned)col[e];
    }
}

// ---------------------------------------------------------------------------
// MFMA GEMM: h[N,J] = x[N,K] @ W[K,J], bf16 LDS operands, fp32 accumulate.
// XBF16: input is the SLICED bf16 B table [q][N][24] (layers 2,3; 24%8==0 so
// 8-channel staging groups never cross a slice); else row-major fp32 x (L1).
// SLICED output (J=96): h stored [q][N][24] so the downstream agg's per-XCD
// gather working set is one contiguous 2.4MB stripe (< 4MB L2). R16.
// mfma_f32_16x16x32_bf16 layouts (HW-verified):
//   A: lane holds X[m=lane&15][k=(lane>>4)*8+j]
//   B: lane holds W[k=(lane>>4)*8+j][n=lane&15]
//   D: lane,reg r -> row m=(lane>>4)*4+r, col n=lane&15
// APPLY: previous layer's BN finalize+apply+ReLU fused into x staging
// (conv bias cancels inside BN — mean absorbs it); stats arrive as
// ST_SLICES partial buffers (R14 agg-fused stats), summed here.
// ---------------------------------------------------------------------------
template <int K, int J, bool APPLY, bool XBF16, bool SLICED>
__global__ __launch_bounds__(256)
void gemm_mfma(const void* __restrict__ xin,
               const unsigned short* __restrict__ Wt,  // [J][K] bf16
               const float* __restrict__ stats,
               const float* __restrict__ gamma,
               const float* __restrict__ beta,
               unsigned short* __restrict__ h, int N) {
    constexpr int MT = 64;
    constexpr int SK = K + 8;       // LDS row stride (shorts); rows 16B-aligned
    constexpr int NT = J / 16;
    __shared__ unsigned short Xs[MT * SK];
    __shared__ unsigned short Ws[J * SK];
    __shared__ float scsh_s[APPLY ? 2 * K : 2];

    int tid = threadIdx.x;
    int tileBase = blockIdx.x * MT;

    if (APPLY) {
        if (tid < K) {
            float s = 0.f, sq = 0.f;
#pragma unroll
            for (int sl = 0; sl < ST_SLICES; ++sl) {
                s  += stats[sl * 2 * K + tid];
                sq += stats[sl * 2 * K + K + tid];
            }
            const float invN = 1.f / N_NODES;
            float mean = s * invN;
            float var = sq * invN - mean * mean;
            float sc = gamma[tid] * rsqrtf(var + BN_EPS);
            scsh_s[tid] = sc;
            scsh_s[K + tid] = beta[tid] - mean * sc;
        }
        __syncthreads();
    }

    if (XBF16) {
        const unsigned short* xb = (const unsigned short*)xin;
        for (int i = tid; i < MT * (K / 8); i += 256) {
            int node = i / (K / 8), kq = i % (K / 8);   // 8-channel group
            int gn = min(tileBase + node, N - 1);
            // Sliced input: group kq lives in slice kq/3 at offset (kq%3)*8.
            const unsigned short* src =
                xb + ((size_t)(kq / 3) * N_NODES + gn) * SLC + (kq % 3) * 8;
            ushort4 u0 = *(const ushort4*)(src);
            ushort4 u1 = *(const ushort4*)(src + 4);
            if (APPLY) {
                int kb = kq * 8;
                float v0 = fmaxf(b2f(u0.x) * scsh_s[kb + 0] + scsh_s[K + kb + 0], 0.f);
                float v1 = fmaxf(b2f(u0.y) * scsh_s[kb + 1] + scsh_s[K + kb + 1], 0.f);
                float v2 = fmaxf(b2f(u0.z) * scsh_s[kb + 2] + scsh_s[K + kb + 2], 0.f);
                float v3 = fmaxf(b2f(u0.w) * scsh_s[kb + 3] + scsh_s[K + kb + 3], 0.f);
                float v4 = fmaxf(b2f(u1.x) * scsh_s[kb + 4] + scsh_s[K + kb + 4], 0.f);
                float v5 = fmaxf(b2f(u1.y) * scsh_s[kb + 5] + scsh_s[K + kb + 5], 0.f);
                float v6 = fmaxf(b2f(u1.z) * scsh_s[kb + 6] + scsh_s[K + kb + 6], 0.f);
                float v7 = fmaxf(b2f(u1.w) * scsh_s[kb + 7] + scsh_s[K + kb + 7], 0.f);
                u0 = make_ushort4(f2b(v0), f2b(v1), f2b(v2), f2b(v3));
                u1 = make_ushort4(f2b(v4), f2b(v5), f2b(v6), f2b(v7));
            }
            *(ushort4*)&Xs[node * SK + kq * 8] = u0;
            *(ushort4*)&Xs[node * SK + kq * 8 + 4] = u1;
        }
    } else {
        const float* xf = (const float*)xin;
        for (int i = tid; i < MT * (K / 4); i += 256) {
            int node = i / (K / 4), kq = i % (K / 4);
            int gn = min(tileBase + node, N - 1);
            float4 v = *(const float4*)(xf + (size_t)gn * K + kq * 4);
            ushort4 o = make_ushort4(f2b(v.x), f2b(v.y), f2b(v.z), f2b(v.w));
            *(ushort4*)&Xs[node * SK + kq * 4] = o;
        }
    }
    for (int i = tid; i < J * (K / 4); i += 256) {
        int j = i / (K / 4), kq = i % (K / 4);
        *(ushort4*)&Ws[j * SK + kq * 4] =
            *(const ushort4*)(Wt + (size_t)j * K + kq * 4);
    }
    __syncthreads();

    int lane = tid & 63;
    int w = tid >> 6;
    int m16 = lane & 15;
    int quad = lane >> 4;

    f32x4 acc[NT];
#pragma unroll
    for (int nt = 0; nt < NT; ++nt) acc[nt] = (f32x4){0.f, 0.f, 0.f, 0.f};

    const unsigned short* xrow = &Xs[(w * 16 + m16) * SK];
#pragma unroll
    for (int k0 = 0; k0 < K; k0 += 32) {
        short8 a = *(const short8*)(xrow + k0 + quad * 8);
#pragma unroll
        for (int nt = 0; nt < NT; ++nt) {
            short8 b = *(const short8*)&Ws[(nt * 16 + m16) * SK + k0 + quad * 8];
            acc[nt] = __builtin_amdgcn_mfma_f32_16x16x32_bf16(a, b, acc[nt], 0, 0, 0);
        }
    }

#pragma unroll
    for (int nt = 0; nt < NT; ++nt) {
#pragma unroll
        for (int r = 0; r < 4; ++r) {
            int node = tileBase + w * 16 + quad * 4 + r;
            if (node < N) {
                int c = nt * 16 + m16;
                if (SLICED) {
                    int q = c / SLC, off = c - q * SLC;
                    h[((size_t)q * N_NODES + node) * SLC + off] = f2b(acc[nt][r]);
                } else {
                    h[(size_t)node * J + c] = f2b(acc[nt][r]);
                }
            }
        }
    }
}

// ---------------------------------------------------------------------------
// R16: slice-per-block ELL aggregation for the 96-ch layers.
// blockIdx&3 = channel slice q; with round-robin block->XCD dispatch each
// XCD gathers from ONE contiguous 2.4MB stripe A[q][*][24] (< 4MB L2) ->
// the random h-gather becomes L2-resident instead of spilling to L3.
// pairs are streamed with nontemporal loads to avoid evicting the stripe.
// One node per thread (24ch); writes B sliced (48B/lane coalesced runs,
// single-XCD-owned regions). BN sum/sumsq fused (full-wave butterfly ->
// LDS across waves -> sliced global atomicAdd).
// ---------------------------------------------------------------------------
__global__ __launch_bounds__(256)
void agg_sliced(const unsigned short* __restrict__ A,   // sliced [q][N][24]
                const int* __restrict__ cnt,
                const unsigned int* __restrict__ pairs,
                unsigned short* __restrict__ B,          // sliced [q][N][24]
                float* __restrict__ stats) {
    constexpr int C = SLC;            // 24
    int tid = threadIdx.x;
    int q = blockIdx.x & 3;
    int gb = blockIdx.x >> 2;
    int n = gb * 256 + tid;
    bool valid = n < N_NODES;
    int nn = valid ? n : N_NODES - 1;
    int end = valid ? min(cnt[nn], ELL_CAP) : 0;
    const unsigned* ep = pairs + ((size_t)nn << ELL_SHIFT);
    const unsigned short* hq = A + (size_t)q * N_NODES * C;

    float acc[C];
#pragma unroll
    for (int c = 0; c < C; ++c) acc[c] = 0.f;

    int i = 0;
    for (; i + 1 < end; i += 2) {
        unsigned p0 = __builtin_nontemporal_load(ep + i);
        unsigned p1 = __builtin_nontemporal_load(ep + i + 1);
        float w0 = (float)(p0 >> 16) * EW_INV;
        float w1 = (float)(p1 >> 16) * EW_INV;
        const uint4* r0 = (const uint4*)(hq + (size_t)(p0 & 0xFFFFu) * C);
        const uint4* r1 = (const uint4*)(hq + (size_t)(p1 & 0xFFFFu) * C);
        uint4 v00 = r0[0], v01 = r0[1], v02 = r0[2];
        uint4 v10 = r1[0], v11 = r1[1], v12 = r1[2];
        FMA8(0, v00, w0) FMA8(8, v01, w0) FMA8(16, v02, w0)
        FMA8(0, v10, w1) FMA8(8, v11, w1) FMA8(16, v12, w1)
    }
    if (i < end) {
        unsigned p0 = __builtin_nontemporal_load(ep + i);
        float w0 = (float)(p0 >> 16) * EW_INV;
        const uint4* r0 = (const uint4*)(hq + (size_t)(p0 & 0xFFFFu) * C);
        uint4 v00 = r0[0], v01 = r0[1], v02 = r0[2];
        FMA8(0, v00, w0) FMA8(8, v01, w0) FMA8(16, v02, w0)
    }

    // Round to bf16 in place (stats must see the rounded values).
#pragma unroll
    for (int c = 0; c < C; ++c) acc[c] = b2f(f2b(acc[c]));

    if (valid) {
        uint4 o0, o1, o2;
        o0.x = pack2(acc[0], acc[1]);   o0.y = pack2(acc[2], acc[3]);
        o0.z = pack2(acc[4], acc[5]);   o0.w = pack2(acc[6], acc[7]);
        o1.x = pack2(acc[8], acc[9]);   o1.y = pack2(acc[10], acc[11]);
        o1.z = pack2(acc[12], acc[13]); o1.w = pack2(acc[14], acc[15]);
        o2.x = pack2(acc[16], acc[17]); o2.y = pack2(acc[18], acc[19]);
        o2.z = pack2(acc[20], acc[21]); o2.w = pack2(acc[22], acc[23]);
        uint4* dst = (uint4*)(B + ((size_t)q * N_NODES + n) * C);
        dst[0] = o0; dst[1] = o1; dst[2] = o2;
    }

    // BN stats: full-wave butterfly (64 nodes/wave, same channels).
    __shared__ float shS[4 * C];
    __shared__ float shQ[4 * C];
    int lane = tid & 63, wv = tid >> 6;
#pragma unroll
    for (int c = 0; c < C; ++c) {
        float s = acc[c];
        float sq = s * s;
#pragma unroll
        for (int msk = 1; msk < 64; msk <<= 1) {
            s  += __shfl_xor(s, msk);
            sq += __shfl_xor(sq, msk);
        }
        if (lane == 0) { shS[wv * C + c] = s; shQ[wv * C + c] = sq; }
    }
    __syncthreads();
    if (tid < C) {
        float S = 0.f, Q = 0.f;
#pragma unroll
        for (int w2 = 0; w2 < 4; ++w2) {
            S += shS[w2 * C + tid];
            Q += shQ[w2 * C + tid];
        }
        int sl = gb & (ST_SLICES - 1);
        atomicAdd(&stats[sl * 2 * HID_C + q * C + tid], S);
        atomicAdd(&stats[sl * 2 * HID_C + HID_C + q * C + tid], Q);
    }
}

// ---------------------------------------------------------------------------
// Layer-3 aggregation (row-major h, D=64): 4 threads/node, fused +b3 and
// log_softmax over the 4-lane group (needs all channels -> can't slice).
// ---------------------------------------------------------------------------
__global__ __launch_bounds__(256)
void agg_lsm(const unsigned short* __restrict__ h,   // row-major [N][64]
             const int* __restrict__ cnt,
             const unsigned int* __restrict__ pairs,
             float* __restrict__ outf,
             const float* __restrict__ b3) {
    constexpr int D = OUT_C;
    constexpr int C = D / 4;          // 16
    int tid = threadIdx.x;
    int q = tid & 3;
    int nloc = tid >> 2;
    int n = blockIdx.x * 64 + nloc;
    bool valid = n < N_NODES;
    int nn = valid ? n : N_NODES - 1;
    int end = valid ? min(cnt[nn], ELL_CAP) : 0;
    const unsigned* ep = pairs + ((size_t)nn << ELL_SHIFT);
    const int cbase = q * C;

    float acc[C];
#pragma unroll
    for (int c = 0; c < C; ++c) acc[c] = 0.f;

    int i = 0;
    for (; i + 1 < end; i += 2) {
        unsigned p0 = __builtin_nontemporal_load(ep + i);
        unsigned p1 = __builtin_nontemporal_load(ep + i + 1);
        float w0 = (float)(p0 >> 16) * EW_INV;
        float w1 = (float)(p1 >> 16) * EW_INV;
        const uint4* r0 = (const uint4*)(h + (size_t)(p0 & 0xFFFFu) * D + cbase);
        const uint4* r1 = (const uint4*)(h + (size_t)(p1 & 0xFFFFu) * D + cbase);
        uint4 v00 = r0[0], v01 = r0[1];
        uint4 v10 = r1[0], v11 = r1[1];
        FMA8(0, v00, w0) FMA8(8, v01, w0)
        FMA8(0, v10, w1) FMA8(8, v11, w1)
    }
    if (i < end) {
        unsigned p0 = __builtin_nontemporal_load(ep + i);
        float w0 = (float)(p0 >> 16) * EW_INV;
        const uint4* r0 = (const uint4*)(h + (size_t)(p0 & 0xFFFFu) * D + cbase);
        uint4 v00 = r0[0], v01 = r0[1];
        FMA8(0, v00, w0) FMA8(8, v01, w0)
    }

    float v[C];
#pragma unroll
    for (int c = 0; c < C; ++c) v[c] = acc[c] + b3[cbase + c];
    float m = v[0];
#pragma unroll
    for (int c = 1; c < C; ++c) m = fmaxf(m, v[c]);
    m = fmaxf(m, __shfl_xor(m, 1));
    m = fmaxf(m, __shfl_xor(m, 2));
    float s = 0.f;
#pragma unroll
    for (int c = 0; c < C; ++c) s += expf(v[c] - m);
    s += __shfl_xor(s, 1);
    s += __shfl_xor(s, 2);
    float l = m + logf(s);
    if (valid) {
#pragma unroll
        for (int ch = 0; ch < C / 4; ++ch) {
            float4 o = make_float4(v[ch * 4 + 0] - l, v[ch * 4 + 1] - l,
                                   v[ch * 4 + 2] - l, v[ch * 4 + 3] - l);
            *(float4*)(outf + (size_t)n * D + cbase + ch * 4) = o;
        }
    }
}

extern "C" void kernel_launch(void* const* d_in, const int* in_sizes, int n_in,
                              void* d_out, int out_size, void* d_ws, size_t ws_size,
                              hipStream_t stream) {
    const float* x   = (const float*)d_in[0];
    const float* ew  = (const float*)d_in[1];
    const int*   row = (const int*)d_in[2];
    const int*   col = (const int*)d_in[3];
    const float* W1  = (const float*)d_in[4];
    // b1 = d_in[5], b2 = d_in[7]: cancel inside BatchNorm (see gemm_mfma).
    const float* W2  = (const float*)d_in[6];
    const float* W3  = (const float*)d_in[8];
    const float* b3  = (const float*)d_in[9];
    const float* g1  = (const float*)d_in[10];
    const float* be1 = (const float*)d_in[11];
    const float* g2  = (const float*)d_in[12];
    const float* be2 = (const float*)d_in[13];
    float* out = (float*)d_out;

    // Workspace layout:
    // B bf16[N*96] (sliced) | A bf16[N*96] (sliced/rowmajor) | Wt1|Wt2|Wt3 |
    // pairs uint[N*64] | cnt[N] | stats1[4*192] | stats2[4*192]
    unsigned short* B      = (unsigned short*)d_ws;
    unsigned short* A      = B + (size_t)N_NODES * HID_C;
    unsigned short* Wt1    = A + (size_t)N_NODES * HID_C;
    unsigned short* Wt2    = Wt1 + IN_C * HID_C;
    unsigned short* Wt3    = Wt2 + HID_C * HID_C;
    unsigned int*   pairs  = (unsigned int*)(Wt3 + HID_C * OUT_C);
    int*            cnt    = (int*)(pairs + ((size_t)N_NODES << ELL_SHIFT));
    float*          stats1 = (float*)(cnt + N_NODES);
    float*          stats2 = stats1 + ST_SLICES * 2 * HID_C;

    const int T = 256;
    const int gridE  = (N_EDGES + T - 1) / T;           // 3125 edge chunks
    const int gridG  = (N_NODES + 63) / 64;             // 782 gemm tiles
    const int gridS  = 4 * ((N_NODES + 255) / 256);     // 784 sliced-agg blocks
    const int gridP  = (N_NODES + T - 1) / T;

    // ---- Prep + fill ----
    prep_all<<<gridP, T, 0, stream>>>(W1, W2, W3, Wt1, Wt2, Wt3, cnt, stats1);
    fill_ell<<<gridE * NGRP, T, 0, stream>>>(row, col, ew, cnt, pairs);

    // ---- Layer 1: gemm(128->96, fp32 in, sliced out); agg(+BN1 stats) ----
    gemm_mfma<IN_C, HID_C, false, false, true><<<gridG, T, 0, stream>>>(
        x, Wt1, nullptr, nullptr, nullptr, A, N_NODES);
    agg_sliced<<<gridS, T, 0, stream>>>(A, cnt, pairs, B, stats1);

    // ---- Layer 2: gemm fuses BN1 (sliced in/out); agg(+BN2 stats) ----
    gemm_mfma<HID_C, HID_C, true, true, true><<<gridG, T, 0, stream>>>(
        B, Wt2, stats1, g1, be1, A, N_NODES);
    agg_sliced<<<gridS, T, 0, stream>>>(A, cnt, pairs, B, stats2);

    // ---- Layer 3: gemm fuses BN2 (sliced in, row-major out); agg+LSM ----
    gemm_mfma<HID_C, OUT_C, true, true, false><<<gridG, T, 0, stream>>>(
        B, Wt3, stats2, g2, be2, A, N_NODES);
    agg_lsm<<<gridG, T, 0, stream>>>(A, cnt, pairs, out, b3);
}

// Round 6
// 256.562 us; speedup vs baseline: 2.3463x; 1.3213x over previous
//
#include <hip/hip_runtime.h>
#include <hip/hip_bf16.h>
#include <math.h>

#define N_NODES 50000
#define N_EDGES 800000
#define IN_C 128
#define HID_C 96
#define OUT_C 64
#define BN_EPS 1e-5f

// ELL edge storage: 64 slots/row. deg ~ Poisson(16); P(deg>64) ~ 1e-17 —
// slot>=64 is guarded (skip) to protect memory, never expected to fire.
#define ELL_SHIFT 6
#define ELL_CAP   64

// XCD routing for the ELL fill (R13 winner).
#define NGRP 8
#define GRP_ROWS ((N_NODES + NGRP - 1) / NGRP)   // 6250

// Packed ELL entry: col in low 16 bits (N_NODES < 65536), edge weight as
// 16-bit fixed point in high bits (ew in [0,1); abs err 7.6e-6).
#define EW_SCALE 65535.0f
#define EW_INV   (1.0f / 65535.0f)

// BN stats atomic slicing: 4 slices cut per-address atomic chains 4x.
#define ST_SLICES 4

typedef __attribute__((ext_vector_type(8))) short short8;   // 8 bf16 = 4 VGPRs
typedef __attribute__((ext_vector_type(4))) float f32x4;    // MFMA acc

static __device__ __forceinline__ unsigned short f2b(float f) {
    __hip_bfloat16 b = __float2bfloat16(f);   // RNE
    return *reinterpret_cast<unsigned short*>(&b);
}
static __device__ __forceinline__ float b2f(unsigned short u) {
    return __uint_as_float((unsigned)u << 16);  // exact
}
static __device__ __forceinline__ unsigned pack2(float a, float b) {
    return (unsigned)f2b(a) | ((unsigned)f2b(b) << 16);
}

// Unpack 8 bf16 from a uint4 / 4 bf16 from a uint2, FMA into acc[B..].
#define FMA8(B, V, W)                                          \
    acc[(B) + 0] += (W) * __uint_as_float((V).x << 16);        \
    acc[(B) + 1] += (W) * __uint_as_float((V).x & 0xffff0000u);\
    acc[(B) + 2] += (W) * __uint_as_float((V).y << 16);        \
    acc[(B) + 3] += (W) * __uint_as_float((V).y & 0xffff0000u);\
    acc[(B) + 4] += (W) * __uint_as_float((V).z << 16);        \
    acc[(B) + 5] += (W) * __uint_as_float((V).z & 0xffff0000u);\
    acc[(B) + 6] += (W) * __uint_as_float((V).w << 16);        \
    acc[(B) + 7] += (W) * __uint_as_float((V).w & 0xffff0000u);

#define FMA4(B, V, W)                                          \
    acc[(B) + 0] += (W) * __uint_as_float((V).x << 16);        \
    acc[(B) + 1] += (W) * __uint_as_float((V).x & 0xffff0000u);\
    acc[(B) + 2] += (W) * __uint_as_float((V).y << 16);        \
    acc[(B) + 3] += (W) * __uint_as_float((V).y & 0xffff0000u);

// ---------------------------------------------------------------------------
// Prep (single launch): W[K][J] fp32 -> Wt[J][K] bf16 for all layers, zero
// the ELL counters, zero BN stats (2 buffers x 4 slices x 2*96 floats).
// ---------------------------------------------------------------------------
__global__ void prep_all(const float* __restrict__ W1, const float* __restrict__ W2,
                         const float* __restrict__ W3,
                         unsigned short* __restrict__ Wt1,
                         unsigned short* __restrict__ Wt2,
                         unsigned short* __restrict__ Wt3,
                         int* __restrict__ cnt, float* __restrict__ stats) {
    int i = blockIdx.x * blockDim.x + threadIdx.x;
    const int n1 = IN_C * HID_C, n2 = HID_C * HID_C, n3 = HID_C * OUT_C;
    if (i < n1) {
        int j = i / IN_C, k = i % IN_C;
        Wt1[i] = f2b(W1[k * HID_C + j]);
    } else if (i < n1 + n2) {
        int t = i - n1, j = t / HID_C, k = t % HID_C;
        Wt2[t] = f2b(W2[k * HID_C + j]);
    } else if (i < n1 + n2 + n3) {
        int t = i - n1 - n2, j = t / HID_C, k = t % HID_C;
        Wt3[t] = f2b(W3[k * OUT_C + j]);
    }
    if (i < N_NODES) cnt[i] = 0;
    if (i < 2 * ST_SLICES * 2 * HID_C) stats[i] = 0.f;   // stats1|stats2
}

// ---------------------------------------------------------------------------
// ELL fill, XCD-routed (R13 winner; fill 53us -> under the 43us prof floor).
// ---------------------------------------------------------------------------
__global__ __launch_bounds__(256)
void fill_ell(const int* __restrict__ row, const int* __restrict__ col,
              const float* __restrict__ ew, int* __restrict__ cnt,
              unsigned int* __restrict__ pairs) {
    int g = blockIdx.x & (NGRP - 1);          // row-group -> XCD (heuristic)
    int e = (blockIdx.x >> 3) * 256 + threadIdx.x;
    if (e >= N_EDGES) return;
    int r = row[e];
    int lo = g * GRP_ROWS;
    if ((unsigned)(r - lo) >= (unsigned)GRP_ROWS) return;   // not my group
    int slot = atomicAdd(&cnt[r], 1);
    if (slot < ELL_CAP) {
        unsigned wq = (unsigned)(ew[e] * EW_SCALE + 0.5f);  // [0,1) -> u16
        pairs[((size_t)r << ELL_SHIFT) + slot] = (wq << 16) | (unsigned)col[e];
    }
}

// ---------------------------------------------------------------------------
// MFMA GEMM (R14, unchanged): h[N,J] = x[N,K] @ W[K,J], bf16 LDS operands,
// fp32 accumulate, row-major bf16 h output. XBF16: input table is bf16
// (layers 2,3); else fp32 (layer 1). Block = 256 threads; tile = 64 x J.
// mfma_f32_16x16x32_bf16 layouts (HW-verified):
//   A: lane holds X[m=lane&15][k=(lane>>4)*8+j]
//   B: lane holds W[k=(lane>>4)*8+j][n=lane&15]
//   D: lane,reg r -> row m=(lane>>4)*4+r, col n=lane&15
// APPLY: previous layer's BN finalize+apply+ReLU fused into x staging
// (conv bias cancels inside BN); stats arrive as ST_SLICES partials.
// ---------------------------------------------------------------------------
template <int K, int J, bool APPLY, bool XBF16>
__global__ __launch_bounds__(256)
void gemm_mfma(const void* __restrict__ xin,
               const unsigned short* __restrict__ Wt,  // [J][K] bf16
               const float* __restrict__ stats,
               const float* __restrict__ gamma,
               const float* __restrict__ beta,
               unsigned short* __restrict__ h, int N) {
    constexpr int MT = 64;
    constexpr int SK = K + 8;
    constexpr int NT = J / 16;
    __shared__ unsigned short Xs[MT * SK];
    __shared__ unsigned short Ws[J * SK];
    __shared__ float scsh_s[APPLY ? 2 * K : 2];

    int tid = threadIdx.x;
    int tileBase = blockIdx.x * MT;

    if (APPLY) {
        if (tid < K) {
            float s = 0.f, sq = 0.f;
#pragma unroll
            for (int sl = 0; sl < ST_SLICES; ++sl) {
                s  += stats[sl * 2 * K + tid];
                sq += stats[sl * 2 * K + K + tid];
            }
            const float invN = 1.f / N_NODES;
            float mean = s * invN;
            float var = sq * invN - mean * mean;
            float sc = gamma[tid] * rsqrtf(var + BN_EPS);
            scsh_s[tid] = sc;
            scsh_s[K + tid] = beta[tid] - mean * sc;
        }
        __syncthreads();
    }

    if (XBF16) {
        const unsigned short* xb = (const unsigned short*)xin;
        for (int i = tid; i < MT * (K / 8); i += 256) {
            int node = i / (K / 8), kq = i % (K / 8);
            int gn = min(tileBase + node, N - 1);
            const unsigned short* src = xb + (size_t)gn * K + kq * 8;
            ushort4 u0 = *(const ushort4*)(src);
            ushort4 u1 = *(const ushort4*)(src + 4);
            if (APPLY) {
                int kb = kq * 8;
                float v0 = fmaxf(b2f(u0.x) * scsh_s[kb + 0] + scsh_s[K + kb + 0], 0.f);
                float v1 = fmaxf(b2f(u0.y) * scsh_s[kb + 1] + scsh_s[K + kb + 1], 0.f);
                float v2 = fmaxf(b2f(u0.z) * scsh_s[kb + 2] + scsh_s[K + kb + 2], 0.f);
                float v3 = fmaxf(b2f(u0.w) * scsh_s[kb + 3] + scsh_s[K + kb + 3], 0.f);
                float v4 = fmaxf(b2f(u1.x) * scsh_s[kb + 4] + scsh_s[K + kb + 4], 0.f);
                float v5 = fmaxf(b2f(u1.y) * scsh_s[kb + 5] + scsh_s[K + kb + 5], 0.f);
                float v6 = fmaxf(b2f(u1.z) * scsh_s[kb + 6] + scsh_s[K + kb + 6], 0.f);
                float v7 = fmaxf(b2f(u1.w) * scsh_s[kb + 7] + scsh_s[K + kb + 7], 0.f);
                u0 = make_ushort4(f2b(v0), f2b(v1), f2b(v2), f2b(v3));
                u1 = make_ushort4(f2b(v4), f2b(v5), f2b(v6), f2b(v7));
            }
            *(ushort4*)&Xs[node * SK + kq * 8] = u0;
            *(ushort4*)&Xs[node * SK + kq * 8 + 4] = u1;
        }
    } else {
        const float* xf = (const float*)xin;
        for (int i = tid; i < MT * (K / 4); i += 256) {
            int node = i / (K / 4), kq = i % (K / 4);
            int gn = min(tileBase + node, N - 1);
            float4 v = *(const float4*)(xf + (size_t)gn * K + kq * 4);
            ushort4 o = make_ushort4(f2b(v.x), f2b(v.y), f2b(v.z), f2b(v.w));
            *(ushort4*)&Xs[node * SK + kq * 4] = o;
        }
    }
    for (int i = tid; i < J * (K / 4); i += 256) {
        int j = i / (K / 4), kq = i % (K / 4);
        *(ushort4*)&Ws[j * SK + kq * 4] =
            *(const ushort4*)(Wt + (size_t)j * K + kq * 4);
    }
    __syncthreads();

    int lane = tid & 63;
    int w = tid >> 6;
    int m16 = lane & 15;
    int quad = lane >> 4;

    f32x4 acc[NT];
#pragma unroll
    for (int nt = 0; nt < NT; ++nt) acc[nt] = (f32x4){0.f, 0.f, 0.f, 0.f};

    const unsigned short* xrow = &Xs[(w * 16 + m16) * SK];
#pragma unroll
    for (int k0 = 0; k0 < K; k0 += 32) {
        short8 a = *(const short8*)(xrow + k0 + quad * 8);
#pragma unroll
        for (int nt = 0; nt < NT; ++nt) {
            short8 b = *(const short8*)&Ws[(nt * 16 + m16) * SK + k0 + quad * 8];
            acc[nt] = __builtin_amdgcn_mfma_f32_16x16x32_bf16(a, b, acc[nt], 0, 0, 0);
        }
    }

#pragma unroll
    for (int nt = 0; nt < NT; ++nt) {
#pragma unroll
        for (int r = 0; r < 4; ++r) {
            int node = tileBase + w * 16 + quad * 4 + r;
            if (node < N)
                h[(size_t)node * J + nt * 16 + m16] = f2b(acc[nt][r]);
        }
    }
}

// ---------------------------------------------------------------------------
// R17: 96-ch aggregation, 8 threads/node (C=12), 32 nodes/block, grid 1563.
// Rationale: R16 counters showed the agg is LATENCY-bound (VALUBusy 10%,
// BW 15%, occupancy 24%) and grid-limited at 782 blocks (~12 waves/CU).
// TPN 4->8 doubles waves/CU (~24) and halves the per-thread FMA chain;
// 4-edge unroll + uint4 pair load gives 12 independent h-loads in flight.
// Layout stays R14 row-major (R16's sliced layout regressed: L2 thrash from
// B write-allocate + lost intra-wave coalescing; ledger −73us).
// BN sum/sumsq fused (8-lane-slice butterfly over the wave's 8 nodes ->
// LDS across waves -> sliced global atomicAdd).
// ---------------------------------------------------------------------------
__global__ __launch_bounds__(256)
void agg96(const unsigned short* __restrict__ h,     // row-major [N][96]
           const int* __restrict__ cnt,
           const unsigned int* __restrict__ pairs,
           unsigned short* __restrict__ outb,        // row-major [N][96]
           float* __restrict__ stats) {
    constexpr int D = HID_C, C = 12;
    int tid = threadIdx.x;
    int q = tid & 7;
    int nloc = tid >> 3;              // 0..31
    int n = blockIdx.x * 32 + nloc;
    bool valid = n < N_NODES;
    int nn = valid ? n : N_NODES - 1;
    int end = valid ? min(cnt[nn], ELL_CAP) : 0;
    const unsigned* ep = pairs + ((size_t)nn << ELL_SHIFT);
    const int cbase = q * C;          // byte offset q*24: 8B-aligned

    float acc[C];
#pragma unroll
    for (int c = 0; c < C; ++c) acc[c] = 0.f;

    int i = 0;
    for (; i + 3 < end; i += 4) {
        uint4 p = *(const uint4*)(ep + i);          // 4 packed edges, 16B
        float w0 = (float)(p.x >> 16) * EW_INV;
        float w1 = (float)(p.y >> 16) * EW_INV;
        float w2 = (float)(p.z >> 16) * EW_INV;
        float w3 = (float)(p.w >> 16) * EW_INV;
        const unsigned short* r0 = h + (size_t)(p.x & 0xFFFFu) * D + cbase;
        const unsigned short* r1 = h + (size_t)(p.y & 0xFFFFu) * D + cbase;
        const unsigned short* r2 = h + (size_t)(p.z & 0xFFFFu) * D + cbase;
        const unsigned short* r3 = h + (size_t)(p.w & 0xFFFFu) * D + cbase;
        // Issue all 12 loads before any FMA (MLP).
        uint2 a0 = *(const uint2*)(r0), a1 = *(const uint2*)(r0 + 4), a2 = *(const uint2*)(r0 + 8);
        uint2 b0 = *(const uint2*)(r1), b1 = *(const uint2*)(r1 + 4), b2 = *(const uint2*)(r1 + 8);
        uint2 c0 = *(const uint2*)(r2), c1 = *(const uint2*)(r2 + 4), c2 = *(const uint2*)(r2 + 8);
        uint2 d0 = *(const uint2*)(r3), d1 = *(const uint2*)(r3 + 4), d2 = *(const uint2*)(r3 + 8);
        FMA4(0, a0, w0) FMA4(4, a1, w0) FMA4(8, a2, w0)
        FMA4(0, b0, w1) FMA4(4, b1, w1) FMA4(8, b2, w1)
        FMA4(0, c0, w2) FMA4(4, c1, w2) FMA4(8, c2, w2)
        FMA4(0, d0, w3) FMA4(4, d1, w3) FMA4(8, d2, w3)
    }
    for (; i < end; ++i) {
        unsigned p = ep[i];
        float w = (float)(p >> 16) * EW_INV;
        const unsigned short* r0 = h + (size_t)(p & 0xFFFFu) * D + cbase;
        uint2 a0 = *(const uint2*)(r0), a1 = *(const uint2*)(r0 + 4), a2 = *(const uint2*)(r0 + 8);
        FMA4(0, a0, w) FMA4(4, a1, w) FMA4(8, a2, w)
    }

    // Round to bf16 in place (stats must see the rounded values).
#pragma unroll
    for (int c = 0; c < C; ++c) acc[c] = b2f(f2b(acc[c]));

    if (valid) {
        unsigned short* dst = outb + (size_t)n * D + cbase;
        uint2 o0, o1, o2;
        o0.x = pack2(acc[0], acc[1]);   o0.y = pack2(acc[2], acc[3]);
        o1.x = pack2(acc[4], acc[5]);   o1.y = pack2(acc[6], acc[7]);
        o2.x = pack2(acc[8], acc[9]);   o2.y = pack2(acc[10], acc[11]);
        *(uint2*)(dst) = o0; *(uint2*)(dst + 4) = o1; *(uint2*)(dst + 8) = o2;
    }

    // BN stats: butterfly over the wave's 8 nodes (masks 8/16/32), then LDS
    // across the 4 waves, then sliced global atomicAdd.
    __shared__ float shS[4 * 8 * C];
    __shared__ float shQ[4 * 8 * C];
    int lane = tid & 63, wv = tid >> 6;
#pragma unroll
    for (int c = 0; c < C; ++c) {
        float s = acc[c];             // invalid nodes contribute 0
        float sq = s * s;
        s  += __shfl_xor(s, 8);  sq += __shfl_xor(sq, 8);
        s  += __shfl_xor(s, 16); sq += __shfl_xor(sq, 16);
        s  += __shfl_xor(s, 32); sq += __shfl_xor(sq, 32);
        if (lane < 8) { shS[(wv * 8 + lane) * C + c] = s;
                        shQ[(wv * 8 + lane) * C + c] = sq; }
    }
    __syncthreads();
    if (tid < D) {
        int qq = tid / C, cl = tid % C;   // global channel == tid
        float S = 0.f, Q = 0.f;
#pragma unroll
        for (int w2 = 0; w2 < 4; ++w2) {
            S += shS[(w2 * 8 + qq) * C + cl];
            Q += shQ[(w2 * 8 + qq) * C + cl];
        }
        int sl = blockIdx.x & (ST_SLICES - 1);
        atomicAdd(&stats[sl * 2 * D + tid], S);
        atomicAdd(&stats[sl * 2 * D + D + tid], Q);
    }
}

// ---------------------------------------------------------------------------
// R17: layer-3 aggregation + b3 + log_softmax. 8 threads/node (C=8),
// 32 nodes/block, grid 1563; 4-edge unroll, one uint4 h-load per edge.
// ---------------------------------------------------------------------------
__global__ __launch_bounds__(256)
void agg64_lsm(const unsigned short* __restrict__ h,  // row-major [N][64]
               const int* __restrict__ cnt,
               const unsigned int* __restrict__ pairs,
               float* __restrict__ outf,
               const float* __restrict__ b3) {
    constexpr int D = OUT_C, C = 8;
    int tid = threadIdx.x;
    int q = tid & 7;
    int nloc = tid >> 3;              // 0..31
    int n = blockIdx.x * 32 + nloc;
    bool valid = n < N_NODES;
    int nn = valid ? n : N_NODES - 1;
    int end = valid ? min(cnt[nn], ELL_CAP) : 0;
    const unsigned* ep = pairs + ((size_t)nn << ELL_SHIFT);
    const int cbase = q * C;          // byte offset q*16: 16B-aligned

    float acc[C];
#pragma unroll
    for (int c = 0; c < C; ++c) acc[c] = 0.f;

    int i = 0;
    for (; i + 3 < end; i += 4) {
        uint4 p = *(const uint4*)(ep + i);
        float w0 = (float)(p.x >> 16) * EW_INV;
        float w1 = (float)(p.y >> 16) * EW_INV;
        float w2 = (float)(p.z >> 16) * EW_INV;
        float w3 = (float)(p.w >> 16) * EW_INV;
        uint4 v0 = *(const uint4*)(h + (size_t)(p.x & 0xFFFFu) * D + cbase);
        uint4 v1 = *(const uint4*)(h + (size_t)(p.y & 0xFFFFu) * D + cbase);
        uint4 v2 = *(const uint4*)(h + (size_t)(p.z & 0xFFFFu) * D + cbase);
        uint4 v3 = *(const uint4*)(h + (size_t)(p.w & 0xFFFFu) * D + cbase);
        FMA8(0, v0, w0)
        FMA8(0, v1, w1)
        FMA8(0, v2, w2)
        FMA8(0, v3, w3)
    }
    for (; i < end; ++i) {
        unsigned p = ep[i];
        float w = (float)(p >> 16) * EW_INV;
        uint4 v = *(const uint4*)(h + (size_t)(p & 0xFFFFu) * D + cbase);
        FMA8(0, v, w)
    }

    float v[C];
#pragma unroll
    for (int c = 0; c < C; ++c) v[c] = acc[c] + b3[cbase + c];
    float m = v[0];
#pragma unroll
    for (int c = 1; c < C; ++c) m = fmaxf(m, v[c]);
    m = fmaxf(m, __shfl_xor(m, 1));
    m = fmaxf(m, __shfl_xor(m, 2));
    m = fmaxf(m, __shfl_xor(m, 4));
    float s = 0.f;
#pragma unroll
    for (int c = 0; c < C; ++c) s += expf(v[c] - m);
    s += __shfl_xor(s, 1);
    s += __shfl_xor(s, 2);
    s += __shfl_xor(s, 4);
    float l = m + logf(s);
    if (valid) {
        float4 o0 = make_float4(v[0] - l, v[1] - l, v[2] - l, v[3] - l);
        float4 o1 = make_float4(v[4] - l, v[5] - l, v[6] - l, v[7] - l);
        float* dst = outf + (size_t)n * D + cbase;
        *(float4*)(dst) = o0;
        *(float4*)(dst + 4) = o1;
    }
}

extern "C" void kernel_launch(void* const* d_in, const int* in_sizes, int n_in,
                              void* d_out, int out_size, void* d_ws, size_t ws_size,
                              hipStream_t stream) {
    const float* x   = (const float*)d_in[0];
    const float* ew  = (const float*)d_in[1];
    const int*   row = (const int*)d_in[2];
    const int*   col = (const int*)d_in[3];
    const float* W1  = (const float*)d_in[4];
    // b1 = d_in[5], b2 = d_in[7]: cancel inside BatchNorm (see gemm_mfma).
    const float* W2  = (const float*)d_in[6];
    const float* W3  = (const float*)d_in[8];
    const float* b3  = (const float*)d_in[9];
    const float* g1  = (const float*)d_in[10];
    const float* be1 = (const float*)d_in[11];
    const float* g2  = (const float*)d_in[12];
    const float* be2 = (const float*)d_in[13];
    float* out = (float*)d_out;

    // Workspace layout:
    // B bf16[N*96] | A bf16[N*96] | Wt1|Wt2|Wt3 bf16 | pairs uint[N*64] |
    // cnt[N] | stats1[4*192] | stats2[4*192]
    unsigned short* B      = (unsigned short*)d_ws;
    unsigned short* A      = B + (size_t)N_NODES * HID_C;
    unsigned short* Wt1    = A + (size_t)N_NODES * HID_C;
    unsigned short* Wt2    = Wt1 + IN_C * HID_C;
    unsigned short* Wt3    = Wt2 + HID_C * HID_C;
    unsigned int*   pairs  = (unsigned int*)(Wt3 + HID_C * OUT_C);
    int*            cnt    = (int*)(pairs + ((size_t)N_NODES << ELL_SHIFT));
    float*          stats1 = (float*)(cnt + N_NODES);
    float*          stats2 = stats1 + ST_SLICES * 2 * HID_C;

    const int T = 256;
    const int gridE  = (N_EDGES + T - 1) / T;        // 3125 edge chunks
    const int gridG  = (N_NODES + 63) / 64;          // 782 gemm tiles
    const int gridA  = (N_NODES + 31) / 32;          // 1563 agg blocks (R17)
    const int gridP  = (N_NODES + T - 1) / T;

    // ---- Prep + fill ----
    prep_all<<<gridP, T, 0, stream>>>(W1, W2, W3, Wt1, Wt2, Wt3, cnt, stats1);
    fill_ell<<<gridE * NGRP, T, 0, stream>>>(row, col, ew, cnt, pairs);

    // ---- Layer 1: gemm(128->96); agg(+BN1 stats) ----
    gemm_mfma<IN_C, HID_C, false, false><<<gridG, T, 0, stream>>>(
        x, Wt1, nullptr, nullptr, nullptr, A, N_NODES);
    agg96<<<gridA, T, 0, stream>>>(A, cnt, pairs, B, stats1);

    // ---- Layer 2: gemm fuses BN1 finalize+apply+ReLU; agg(+BN2 stats) ----
    gemm_mfma<HID_C, HID_C, true, true><<<gridG, T, 0, stream>>>(
        B, Wt2, stats1, g1, be1, A, N_NODES);
    agg96<<<gridA, T, 0, stream>>>(A, cnt, pairs, B, stats2);

    // ---- Layer 3: gemm fuses BN2; agg fuses +b3 and log_softmax -> out ----
    gemm_mfma<HID_C, OUT_C, true, true><<<gridG, T, 0, stream>>>(
        B, Wt3, stats2, g2, be2, A, N_NODES);
    agg64_lsm<<<gridA, T, 0, stream>>>(A, cnt, pairs, out, b3);
}